// Round 8
// baseline (535.248 us; speedup 1.0000x reference)
//
#include <hip/hip_runtime.h>
#include <hip/hip_bf16.h>
#include <stdint.h>

#define D 256
#define NBUCK 782            // ceil(100000 / 128) buckets of 128 nodes
#define BSHIFT 7
#define TILE 4096            // edges per block in binning pass

typedef short short8 __attribute__((ext_vector_type(8)));
typedef float f32x4 __attribute__((ext_vector_type(4)));

__device__ __forceinline__ float bf2f(unsigned short u) {
  return __uint_as_float(((unsigned)u) << 16);
}
__device__ __forceinline__ unsigned short f2bf(float f) {
  unsigned u = __float_as_uint(f);
  unsigned r = u + 0x7FFFu + ((u >> 16) & 1u);
  return (unsigned short)(r >> 16);
}

// ---------------- K1: coarse bucket histogram (LDS-binned) ----------------
__global__ void bucket_hist_kernel(const int* __restrict__ src, int* __restrict__ bcount, int E) {
  __shared__ int h[NBUCK];
  for (int i = threadIdx.x; i < NBUCK; i += 256) h[i] = 0;
  __syncthreads();
  int gid = blockIdx.x * 256 + threadIdx.x;
  for (int e = gid; e < E; e += 1024 * 256) atomicAdd(&h[src[e] >> BSHIFT], 1);
  __syncthreads();
  for (int i = threadIdx.x; i < NBUCK; i += 256) {
    int c = h[i];
    if (c) atomicAdd(&bcount[i], c);
  }
}

// ---------------- K2: exclusive scan of bucket counts ----------------
__launch_bounds__(1024)
__global__ void bucket_scan_kernel(const int* __restrict__ bcount, int* __restrict__ bbase,
                                   int* __restrict__ gcursor) {
  __shared__ int sc[2][1024];
  int tid = threadIdx.x;
  sc[0][tid] = (tid < NBUCK) ? bcount[tid] : 0;
  __syncthreads();
  int d = 0;
  for (int off = 1; off < 1024; off <<= 1) {
    int v = sc[d][tid];
    if (tid >= off) v += sc[d][tid - off];
    sc[d ^ 1][tid] = v;
    __syncthreads();
    d ^= 1;
  }
  if (tid < NBUCK) {
    int excl = (tid == 0) ? 0 : sc[d][tid - 1];
    bbase[tid] = excl;
    gcursor[tid] = excl;
  }
}

// ---------------- K3: binning scatter ----------------
// Scattered writes stay inside per-bucket L2-resident windows (r6 lesson:
// globally scattered 4 B writes cost 15x write-amplification).
__launch_bounds__(256)
__global__ void binscatter_kernel(const int* __restrict__ src, const int* __restrict__ dst,
                                  int* __restrict__ gcursor, int* __restrict__ ebuf, int E) {
  __shared__ int hist[NBUCK];
  __shared__ int lstart[1024];
  __shared__ int gbase[NBUCK];
  __shared__ int sc[2][1024];
  __shared__ int stag[TILE];
  __shared__ unsigned short sbuck[TILE];

  int tid = threadIdx.x;
  int base = blockIdx.x * TILE;
  int tilecount = E - base;
  if (tilecount > TILE) tilecount = TILE;

  for (int i = tid; i < NBUCK; i += 256) hist[i] = 0;
  __syncthreads();

  int esrc[16], edst[16];
#pragma unroll
  for (int k = 0; k < 16; k++) {
    int e = base + k * 256 + tid;
    if (e < E) {
      esrc[k] = src[e];
      edst[k] = dst[e];
      atomicAdd(&hist[esrc[k] >> BSHIFT], 1);
    } else {
      esrc[k] = -1;
      edst[k] = 0;
    }
  }
  __syncthreads();

  for (int i = tid; i < 1024; i += 256) sc[0][i] = (i < NBUCK) ? hist[i] : 0;
  __syncthreads();
  int d = 0;
  for (int off = 1; off < 1024; off <<= 1) {
    for (int i = tid; i < 1024; i += 256) {
      int v = sc[d][i];
      if (i >= off) v += sc[d][i - off];
      sc[d ^ 1][i] = v;
    }
    __syncthreads();
    d ^= 1;
  }
  for (int i = tid; i < 1024; i += 256) lstart[i] = (i == 0) ? 0 : sc[d][i - 1];
  __syncthreads();

  for (int b = tid; b < NBUCK; b += 256) {
    int c = hist[b];
    if (c) gbase[b] = atomicAdd(&gcursor[b], c);
  }
  __syncthreads();

  for (int i = tid; i < NBUCK; i += 256) hist[i] = 0;
  __syncthreads();

#pragma unroll
  for (int k = 0; k < 16; k++) {
    if (esrc[k] >= 0) {
      int b = esrc[k] >> BSHIFT;
      int r = atomicAdd(&hist[b], 1);
      int pos = lstart[b] + r;
      stag[pos] = edst[k] | ((esrc[k] & 127) << 20);
      sbuck[pos] = (unsigned short)b;
    }
  }
  __syncthreads();

  for (int s = tid; s < tilecount; s += 256) {
    int b = sbuck[s];
    ebuf[gbase[b] + (s - lstart[b])] = stag[s];
  }
}

// ---------------- K4: per-bucket counting sort ----------------
// 128 nodes/bucket -> 782 blocks: all co-resident (3128 waves vs 8192 cap),
// per-block serial work halved vs the 391-block r7 version (which ran the
// machine at <20% wave occupancy with a 1.53x tail).
__launch_bounds__(256)
__global__ void bucketsort_kernel(const int* __restrict__ ebuf, const int* __restrict__ bbase,
                                  const int* __restrict__ bcount, int* __restrict__ csr,
                                  int2* __restrict__ meta, float* __restrict__ rnorm, int N) {
  __shared__ int ncnt[128];
  __shared__ int nstart[128];
  __shared__ int sc[2][128];
  int tid = threadIdx.x;
  int b = blockIdx.x;
  int base = bbase[b];
  int cnt = bcount[b];
  int node0 = b << BSHIFT;

  if (tid < 128) ncnt[tid] = 0;
  __syncthreads();
  for (int s = tid; s < cnt; s += 256) {
    int v = ebuf[base + s];
    atomicAdd(&ncnt[v >> 20], 1);
  }
  __syncthreads();

  int mycnt = 0;
  if (tid < 128) {
    mycnt = ncnt[tid];
    sc[0][tid] = mycnt;
  }
  __syncthreads();
  int d = 0;
  for (int off = 1; off < 128; off <<= 1) {
    if (tid < 128) {
      int v = sc[d][tid];
      if (tid >= off) v += sc[d][tid - off];
      sc[d ^ 1][tid] = v;
    }
    __syncthreads();
    d ^= 1;
  }
  if (tid < 128) {
    nstart[tid] = (tid == 0) ? 0 : sc[d][tid - 1];
    int node = node0 + tid;
    if (node < N) {
      meta[node] = make_int2(base + nstart[tid], mycnt);
      rnorm[node] = rsqrtf((float)(mycnt + 1));
    }
    ncnt[tid] = 0;
  }
  __syncthreads();

  for (int s = tid; s < cnt; s += 256) {
    int v = ebuf[base + s];
    int nl = v >> 20;
    int r = atomicAdd(&ncnt[nl], 1);
    csr[base + nstart[nl] + r] = v & 0xFFFFF;
  }
}

// ---------------- fp32 -> bf16 conversion for W only ----------------
__global__ void convw_kernel(const float* __restrict__ w, unsigned short* __restrict__ wb) {
  int i4 = blockIdx.x * 256 + threadIdx.x;
  int elem = i4 * 4;
  const float4 v = *(const float4*)&w[elem];
  ushort4 o;
  o.x = f2bf(v.x); o.y = f2bf(v.y); o.z = f2bf(v.z); o.w = f2bf(v.w);
  *(ushort4*)&wb[elem] = o;
}

// ---------------- fused bf16 MFMA GEMM: hs = rsqrt(deg) * (x @ W^T) ----------
// r4 structure exactly (BN=128, grid (NPAD/128, 2), acc[4][4]) — only the A
// staging reads f32 x directly with in-register f2bf (fuses old convx;
// r5's regression was BN=256 + acc[4][8], not the staging per se).
// Pad rows (gr >= n): staged zeros AND rn = 0 -> hb pad rows are zeros.
__launch_bounds__(256)
__global__ void gemm_kernel(const float* __restrict__ X,
                            const unsigned short* __restrict__ B,
                            unsigned short* __restrict__ Hout,
                            const float* __restrict__ rnorm, int n) {
  __shared__ unsigned short sA[128 * 32];
  __shared__ unsigned short sB[128 * 32];
  int tid = threadIdx.x;
  int wave = tid >> 6, lane = tid & 63;
  int wm = wave >> 1, wn = wave & 1;
  int l16 = lane & 15, quad = lane >> 4;
  int arow0 = blockIdx.x * 128;
  int brow0 = blockIdx.y * 128;

  f32x4 acc[4][4];
  const f32x4 zero = {0.f, 0.f, 0.f, 0.f};
#pragma unroll
  for (int i = 0; i < 4; i++)
#pragma unroll
    for (int j = 0; j < 4; j++) acc[i][j] = zero;

  for (int k0 = 0; k0 < 256; k0 += 32) {
#pragma unroll
    for (int it = 0; it < 2; ++it) {
      int c = it * 256 + tid;
      int row = c >> 2, cc = (c & 3) * 8;
      int grow = arow0 + row;
      ushort4 lo = make_ushort4(0, 0, 0, 0), hi = make_ushort4(0, 0, 0, 0);
      if (grow < n) {
        const float4 v0 = *(const float4*)&X[(size_t)grow * 256 + k0 + cc];
        const float4 v1 = *(const float4*)&X[(size_t)grow * 256 + k0 + cc + 4];
        lo.x = f2bf(v0.x); lo.y = f2bf(v0.y); lo.z = f2bf(v0.z); lo.w = f2bf(v0.w);
        hi.x = f2bf(v1.x); hi.y = f2bf(v1.y); hi.z = f2bf(v1.z); hi.w = f2bf(v1.w);
      }
      *(ushort4*)&sA[c * 8] = lo;
      *(ushort4*)&sA[c * 8 + 4] = hi;
      *(int4*)&sB[c * 8] = *(const int4*)&B[(brow0 + row) * 256 + k0 + cc];
    }
    __syncthreads();
    short8 af[4], bfr[4];
#pragma unroll
    for (int i = 0; i < 4; i++)
      af[i] = *(const short8*)&sA[(wm * 64 + i * 16 + l16) * 32 + quad * 8];
#pragma unroll
    for (int j = 0; j < 4; j++)
      bfr[j] = *(const short8*)&sB[(wn * 64 + j * 16 + l16) * 32 + quad * 8];
#pragma unroll
    for (int i = 0; i < 4; i++)
#pragma unroll
      for (int j = 0; j < 4; j++)
        acc[i][j] = __builtin_amdgcn_mfma_f32_16x16x32_bf16(af[i], bfr[j], acc[i][j], 0, 0, 0);
    __syncthreads();
  }

#pragma unroll
  for (int i = 0; i < 4; i++) {
    int rowb = arow0 + wm * 64 + i * 16 + quad * 4;
#pragma unroll
    for (int r = 0; r < 4; r++) {
      int gr = rowb + r;
      float rn = (gr < n) ? rnorm[gr] : 0.f;
#pragma unroll
      for (int j = 0; j < 4; j++) {
        int col = brow0 + wn * 64 + j * 16 + l16;
        Hout[(size_t)gr * 256 + col] = f2bf(acc[i][j][r] * rn);
      }
    }
  }
}

// ---------------- CSR gather, fused column-split (r7 form, CLOSED) ----------
// 4-line (256 B) wave-loads, lane owns 2 cols; colbase = (bid&1)*128.
// Measured 209.8 us = ~5.05 cyc/64B-line/CU, below the streaming constant
// (6.3): line count E x 8 is the algorithmic floor at bf16 (accuracy floor).
// Residency (r3), width (r2/r4), split-vs-fused (r7) all measured; done.
__launch_bounds__(256)
__global__ void gather_kernel(const unsigned short* __restrict__ hs,
                              const int2* __restrict__ meta,
                              const float* __restrict__ rnorm,
                              const int* __restrict__ csr,
                              float* __restrict__ out, int n) {
  int wave = threadIdx.x >> 6, lane = threadIdx.x & 63;
  int colbase = (blockIdx.x & 1) * 128;
  int node = (blockIdx.x >> 1) * 4 + wave;
  if (node >= n) return;
  long long mm = *(const long long*)&meta[node];
  int start = (int)mm, cnt = (int)(mm >> 32);
  const unsigned short* hcol = hs + colbase + lane * 2;
  float a0 = 0.f, a1 = 0.f;
  for (int base = 0; base < cnt; base += 64) {
    int m = cnt - base;
    if (m > 64) m = 64;
    int idxv = 0;
    if (lane < m) idxv = csr[start + base + lane];
    int t = 0;
    for (; t + 8 <= m; t += 8) {
      int d0 = __shfl(idxv, t);
      int d1 = __shfl(idxv, t + 1);
      int d2 = __shfl(idxv, t + 2);
      int d3 = __shfl(idxv, t + 3);
      int d4 = __shfl(idxv, t + 4);
      int d5 = __shfl(idxv, t + 5);
      int d6 = __shfl(idxv, t + 6);
      int d7 = __shfl(idxv, t + 7);
      unsigned u0 = *(const unsigned*)&hcol[d0 * 256];
      unsigned u1 = *(const unsigned*)&hcol[d1 * 256];
      unsigned u2 = *(const unsigned*)&hcol[d2 * 256];
      unsigned u3 = *(const unsigned*)&hcol[d3 * 256];
      unsigned u4 = *(const unsigned*)&hcol[d4 * 256];
      unsigned u5 = *(const unsigned*)&hcol[d5 * 256];
      unsigned u6 = *(const unsigned*)&hcol[d6 * 256];
      unsigned u7 = *(const unsigned*)&hcol[d7 * 256];
      a0 += bf2f((unsigned short)u0) + bf2f((unsigned short)u1) +
            bf2f((unsigned short)u2) + bf2f((unsigned short)u3) +
            bf2f((unsigned short)u4) + bf2f((unsigned short)u5) +
            bf2f((unsigned short)u6) + bf2f((unsigned short)u7);
      a1 += bf2f((unsigned short)(u0 >> 16)) + bf2f((unsigned short)(u1 >> 16)) +
            bf2f((unsigned short)(u2 >> 16)) + bf2f((unsigned short)(u3 >> 16)) +
            bf2f((unsigned short)(u4 >> 16)) + bf2f((unsigned short)(u5 >> 16)) +
            bf2f((unsigned short)(u6 >> 16)) + bf2f((unsigned short)(u7 >> 16));
    }
    for (; t < m; ++t) {
      int dd = __shfl(idxv, t);
      unsigned u = *(const unsigned*)&hcol[dd * 256];
      a0 += bf2f((unsigned short)u);
      a1 += bf2f((unsigned short)(u >> 16));
    }
  }
  unsigned us = *(const unsigned*)&hcol[node * 256];
  float rn = rnorm[node];
  float2 o;
  o.x = rn * (a0 + bf2f((unsigned short)us));
  o.y = rn * (a1 + bf2f((unsigned short)(us >> 16)));
  *(float2*)&out[(size_t)node * 256 + colbase + lane * 2] = o;
}

extern "C" void kernel_launch(void* const* d_in, const int* in_sizes, int n_in,
                              void* d_out, int out_size, void* d_ws, size_t ws_size,
                              hipStream_t stream) {
  const float* x = (const float*)d_in[0];
  const float* W = (const float*)d_in[1];
  const int* ei = (const int*)d_in[2];
  float* out = (float*)d_out;

  int N = in_sizes[0] / D;        // 100000
  int E = in_sizes[2] / 2;        // 3200000
  int NPAD = (N + 127) & ~127;
  const int* src = ei;
  const int* dst = ei + E;

  char* p = (char*)d_ws;
  auto alloc = [&](size_t b) {
    char* r = p;
    p += (b + 255) & ~(size_t)255;
    return r;
  };
  unsigned short* wb = (unsigned short*)alloc((size_t)D * D * 2);
  unsigned short* hb = (unsigned short*)alloc((size_t)NPAD * D * 2);
  int* csr = (int*)alloc((size_t)(E + 64) * 4);
  int2* meta = (int2*)alloc((size_t)N * 8);
  float* rnorm = (float*)alloc((size_t)N * 4);
  int* bcount = (int*)alloc(NBUCK * 4);
  int* bbase = (int*)alloc(NBUCK * 4);
  int* gcursor = (int*)alloc(NBUCK * 4);
  // ebuf (E*4 = 12.8 MB) aliases hb (51 MB): dead before gemm writes hb
  int* ebuf = (int*)hb;

  hipMemsetAsync(bcount, 0, NBUCK * 4, stream);
  bucket_hist_kernel<<<1024, 256, 0, stream>>>(src, bcount, E);
  bucket_scan_kernel<<<1, 1024, 0, stream>>>(bcount, bbase, gcursor);
  binscatter_kernel<<<(E + TILE - 1) / TILE, 256, 0, stream>>>(src, dst, gcursor, ebuf, E);
  bucketsort_kernel<<<NBUCK, 256, 0, stream>>>(ebuf, bbase, bcount, csr, meta, rnorm, N);
  convw_kernel<<<(D * D / 4) / 256, 256, 0, stream>>>(W, wb);
  gemm_kernel<<<dim3(NPAD / 128, D / 128), 256, 0, stream>>>(x, wb, hb, rnorm, N);
  gather_kernel<<<2 * ((N + 3) / 4), 256, 0, stream>>>(hb, meta, rnorm, csr, out, N);
}

// Round 9
// 489.254 us; speedup vs baseline: 1.0940x; 1.0940x over previous
//
#include <hip/hip_runtime.h>
#include <hip/hip_bf16.h>
#include <stdint.h>

#define D 256
#define NBUCK 391            // ceil(100000 / 256) buckets of 256 nodes
#define BSHIFT 8
#define TILE 4096            // edges per block in binning pass
#define CAPSH 14             // fixed bucket capacity 16384 (mean 8184, sigma 90)
#define STAGECAP 8704        // LDS staging bound in bucketsort (global fallback past it)

typedef short short8 __attribute__((ext_vector_type(8)));
typedef float f32x4 __attribute__((ext_vector_type(4)));

__device__ __forceinline__ float bf2f(unsigned short u) {
  return __uint_as_float(((unsigned)u) << 16);
}
__device__ __forceinline__ unsigned short f2bf(float f) {
  unsigned u = __float_as_uint(f);
  unsigned r = u + 0x7FFFu + ((u >> 16) & 1u);
  return (unsigned short)(r >> 16);
}

// ---------------- K0: init per-bucket cursors to fixed strides --------------
__global__ void init_kernel(int* __restrict__ gcursor) {
  int i = blockIdx.x * 256 + threadIdx.x;
  if (i < NBUCK) gcursor[i] = i << CAPSH;
}

// ---------------- K1: binning scatter (r7 form; no hist/scan needed) --------
// Scattered writes stay inside per-bucket L2-resident windows (r6 lesson:
// globally scattered 4 B writes cost 15x write-amplification). Bucket bases
// are fixed strides b<<CAPSH, so the histogram+scan dispatches are deleted.
__launch_bounds__(256)
__global__ void binscatter_kernel(const int* __restrict__ src, const int* __restrict__ dst,
                                  int* __restrict__ gcursor, int* __restrict__ ebuf, int E) {
  __shared__ int hist[NBUCK];
  __shared__ int lstart[512];
  __shared__ int gbase[NBUCK];
  __shared__ int sc[2][512];
  __shared__ int stag[TILE];
  __shared__ unsigned short sbuck[TILE];

  int tid = threadIdx.x;
  int base = blockIdx.x * TILE;
  int tilecount = E - base;
  if (tilecount > TILE) tilecount = TILE;

  for (int i = tid; i < NBUCK; i += 256) hist[i] = 0;
  __syncthreads();

  int esrc[16], edst[16];
#pragma unroll
  for (int k = 0; k < 16; k++) {
    int e = base + k * 256 + tid;
    if (e < E) {
      esrc[k] = src[e];
      edst[k] = dst[e];
      atomicAdd(&hist[esrc[k] >> BSHIFT], 1);
    } else {
      esrc[k] = -1;
      edst[k] = 0;
    }
  }
  __syncthreads();

  for (int i = tid; i < 512; i += 256) sc[0][i] = (i < NBUCK) ? hist[i] : 0;
  __syncthreads();
  int d = 0;
  for (int off = 1; off < 512; off <<= 1) {
    for (int i = tid; i < 512; i += 256) {
      int v = sc[d][i];
      if (i >= off) v += sc[d][i - off];
      sc[d ^ 1][i] = v;
    }
    __syncthreads();
    d ^= 1;
  }
  for (int i = tid; i < 512; i += 256) lstart[i] = (i == 0) ? 0 : sc[d][i - 1];
  __syncthreads();

  for (int b = tid; b < NBUCK; b += 256) {
    int c = hist[b];
    if (c) gbase[b] = atomicAdd(&gcursor[b], c);
  }
  __syncthreads();

  for (int i = tid; i < NBUCK; i += 256) hist[i] = 0;
  __syncthreads();

#pragma unroll
  for (int k = 0; k < 16; k++) {
    if (esrc[k] >= 0) {
      int b = esrc[k] >> BSHIFT;
      int r = atomicAdd(&hist[b], 1);
      int pos = lstart[b] + r;
      stag[pos] = edst[k] | ((esrc[k] & 255) << 20);
      sbuck[pos] = (unsigned short)b;
    }
  }
  __syncthreads();

  for (int s = tid; s < tilecount; s += 256) {
    int b = sbuck[s];
    int pos = gbase[b] + (s - lstart[b]);
    if (pos < ((b + 1) << CAPSH))          // 91-sigma overflow clamp
      ebuf[pos] = stag[s];
  }
}

// ---------------- K2: per-bucket counting sort (LDS-staged) ----------------
// base/cnt come from the fixed stride + final cursor; the bucket's ebuf
// segment (mean 8184 ints = 32 KB) is staged once into LDS so both counting
// passes read LDS instead of strided global at 391-block low occupancy.
__launch_bounds__(256)
__global__ void bucketsort_kernel(const int* __restrict__ ebuf, const int* __restrict__ gcursor,
                                  int* __restrict__ csr,
                                  int2* __restrict__ meta, float* __restrict__ rnorm, int N) {
  __shared__ int seg[STAGECAP];
  __shared__ int ncnt[256];
  __shared__ int nstart[256];
  __shared__ int sc[2][256];
  int tid = threadIdx.x;
  int b = blockIdx.x;
  int base = b << CAPSH;
  int cnt = gcursor[b] - base;
  int node0 = b << BSHIFT;

  int lim = (cnt < STAGECAP) ? cnt : STAGECAP;
  for (int s = tid; s < lim; s += 256) seg[s] = ebuf[base + s];
  ncnt[tid] = 0;
  __syncthreads();

  for (int s = tid; s < cnt; s += 256) {
    int v = (s < STAGECAP) ? seg[s] : ebuf[base + s];
    atomicAdd(&ncnt[v >> 20], 1);
  }
  __syncthreads();

  int mycnt = ncnt[tid];
  sc[0][tid] = mycnt;
  __syncthreads();
  int d = 0;
  for (int off = 1; off < 256; off <<= 1) {
    int v = sc[d][tid];
    if (tid >= off) v += sc[d][tid - off];
    sc[d ^ 1][tid] = v;
    __syncthreads();
    d ^= 1;
  }
  nstart[tid] = (tid == 0) ? 0 : sc[d][tid - 1];
  __syncthreads();

  int node = node0 + tid;
  if (node < N) {
    meta[node] = make_int2(base + nstart[tid], mycnt);
    rnorm[node] = rsqrtf((float)(mycnt + 1));
  }

  ncnt[tid] = 0;
  __syncthreads();
  for (int s = tid; s < cnt; s += 256) {
    int v = (s < STAGECAP) ? seg[s] : ebuf[base + s];
    int nl = v >> 20;
    int r = atomicAdd(&ncnt[nl], 1);
    csr[base + nstart[nl] + r] = v & 0xFFFFF;
  }
}

// ---------------- fp32 -> bf16 conversion for W only ----------------
__global__ void convw_kernel(const float* __restrict__ w, unsigned short* __restrict__ wb) {
  int i4 = blockIdx.x * 256 + threadIdx.x;
  int elem = i4 * 4;
  const float4 v = *(const float4*)&w[elem];
  ushort4 o;
  o.x = f2bf(v.x); o.y = f2bf(v.y); o.z = f2bf(v.z); o.w = f2bf(v.w);
  *(ushort4*)&wb[elem] = o;
}

// ---------------- fused bf16 MFMA GEMM: hs = rsqrt(deg) * (x @ W^T) ----------
// r7-proven: BN=128, grid (NPAD/128, 2), acc[4][4]; A staged from f32 x with
// in-register f2bf (r5 proved BN=256/acc[4][8] regresses — do not widen).
// Pad rows (gr >= n): staged zeros AND rn = 0 -> hb pad rows are zeros.
__launch_bounds__(256)
__global__ void gemm_kernel(const float* __restrict__ X,
                            const unsigned short* __restrict__ B,
                            unsigned short* __restrict__ Hout,
                            const float* __restrict__ rnorm, int n) {
  __shared__ unsigned short sA[128 * 32];
  __shared__ unsigned short sB[128 * 32];
  int tid = threadIdx.x;
  int wave = tid >> 6, lane = tid & 63;
  int wm = wave >> 1, wn = wave & 1;
  int l16 = lane & 15, quad = lane >> 4;
  int arow0 = blockIdx.x * 128;
  int brow0 = blockIdx.y * 128;

  f32x4 acc[4][4];
  const f32x4 zero = {0.f, 0.f, 0.f, 0.f};
#pragma unroll
  for (int i = 0; i < 4; i++)
#pragma unroll
    for (int j = 0; j < 4; j++) acc[i][j] = zero;

  for (int k0 = 0; k0 < 256; k0 += 32) {
#pragma unroll
    for (int it = 0; it < 2; ++it) {
      int c = it * 256 + tid;
      int row = c >> 2, cc = (c & 3) * 8;
      int grow = arow0 + row;
      ushort4 lo = make_ushort4(0, 0, 0, 0), hi = make_ushort4(0, 0, 0, 0);
      if (grow < n) {
        const float4 v0 = *(const float4*)&X[(size_t)grow * 256 + k0 + cc];
        const float4 v1 = *(const float4*)&X[(size_t)grow * 256 + k0 + cc + 4];
        lo.x = f2bf(v0.x); lo.y = f2bf(v0.y); lo.z = f2bf(v0.z); lo.w = f2bf(v0.w);
        hi.x = f2bf(v1.x); hi.y = f2bf(v1.y); hi.z = f2bf(v1.z); hi.w = f2bf(v1.w);
      }
      *(ushort4*)&sA[c * 8] = lo;
      *(ushort4*)&sA[c * 8 + 4] = hi;
      *(int4*)&sB[c * 8] = *(const int4*)&B[(brow0 + row) * 256 + k0 + cc];
    }
    __syncthreads();
    short8 af[4], bfr[4];
#pragma unroll
    for (int i = 0; i < 4; i++)
      af[i] = *(const short8*)&sA[(wm * 64 + i * 16 + l16) * 32 + quad * 8];
#pragma unroll
    for (int j = 0; j < 4; j++)
      bfr[j] = *(const short8*)&sB[(wn * 64 + j * 16 + l16) * 32 + quad * 8];
#pragma unroll
    for (int i = 0; i < 4; i++)
#pragma unroll
      for (int j = 0; j < 4; j++)
        acc[i][j] = __builtin_amdgcn_mfma_f32_16x16x32_bf16(af[i], bfr[j], acc[i][j], 0, 0, 0);
    __syncthreads();
  }

#pragma unroll
  for (int i = 0; i < 4; i++) {
    int rowb = arow0 + wm * 64 + i * 16 + quad * 4;
#pragma unroll
    for (int r = 0; r < 4; r++) {
      int gr = rowb + r;
      float rn = (gr < n) ? rnorm[gr] : 0.f;
#pragma unroll
      for (int j = 0; j < 4; j++) {
        int col = brow0 + wn * 64 + j * 16 + l16;
        Hout[(size_t)gr * 256 + col] = f2bf(acc[i][j][r] * rn);
      }
    }
  }
}

// ---------------- CSR gather, fused column-split (r7 form, CLOSED) ----------
// 4-line (256 B) wave-loads, lane owns 2 cols; colbase = (bid&1)*128.
// Measured 209.8 us = ~5.05 cyc/64B-line/CU, below the streaming constant
// (6.3): line count E x 8 is the algorithmic floor at bf16 (accuracy floor).
// Residency (r3), width (r2/r4), split-vs-fused (r7) all measured; done.
__launch_bounds__(256)
__global__ void gather_kernel(const unsigned short* __restrict__ hs,
                              const int2* __restrict__ meta,
                              const float* __restrict__ rnorm,
                              const int* __restrict__ csr,
                              float* __restrict__ out, int n) {
  int wave = threadIdx.x >> 6, lane = threadIdx.x & 63;
  int colbase = (blockIdx.x & 1) * 128;
  int node = (blockIdx.x >> 1) * 4 + wave;
  if (node >= n) return;
  long long mm = *(const long long*)&meta[node];
  int start = (int)mm, cnt = (int)(mm >> 32);
  const unsigned short* hcol = hs + colbase + lane * 2;
  float a0 = 0.f, a1 = 0.f;
  for (int base = 0; base < cnt; base += 64) {
    int m = cnt - base;
    if (m > 64) m = 64;
    int idxv = 0;
    if (lane < m) idxv = csr[start + base + lane];
    int t = 0;
    for (; t + 8 <= m; t += 8) {
      int d0 = __shfl(idxv, t);
      int d1 = __shfl(idxv, t + 1);
      int d2 = __shfl(idxv, t + 2);
      int d3 = __shfl(idxv, t + 3);
      int d4 = __shfl(idxv, t + 4);
      int d5 = __shfl(idxv, t + 5);
      int d6 = __shfl(idxv, t + 6);
      int d7 = __shfl(idxv, t + 7);
      unsigned u0 = *(const unsigned*)&hcol[d0 * 256];
      unsigned u1 = *(const unsigned*)&hcol[d1 * 256];
      unsigned u2 = *(const unsigned*)&hcol[d2 * 256];
      unsigned u3 = *(const unsigned*)&hcol[d3 * 256];
      unsigned u4 = *(const unsigned*)&hcol[d4 * 256];
      unsigned u5 = *(const unsigned*)&hcol[d5 * 256];
      unsigned u6 = *(const unsigned*)&hcol[d6 * 256];
      unsigned u7 = *(const unsigned*)&hcol[d7 * 256];
      a0 += bf2f((unsigned short)u0) + bf2f((unsigned short)u1) +
            bf2f((unsigned short)u2) + bf2f((unsigned short)u3) +
            bf2f((unsigned short)u4) + bf2f((unsigned short)u5) +
            bf2f((unsigned short)u6) + bf2f((unsigned short)u7);
      a1 += bf2f((unsigned short)(u0 >> 16)) + bf2f((unsigned short)(u1 >> 16)) +
            bf2f((unsigned short)(u2 >> 16)) + bf2f((unsigned short)(u3 >> 16)) +
            bf2f((unsigned short)(u4 >> 16)) + bf2f((unsigned short)(u5 >> 16)) +
            bf2f((unsigned short)(u6 >> 16)) + bf2f((unsigned short)(u7 >> 16));
    }
    for (; t < m; ++t) {
      int dd = __shfl(idxv, t);
      unsigned u = *(const unsigned*)&hcol[dd * 256];
      a0 += bf2f((unsigned short)u);
      a1 += bf2f((unsigned short)(u >> 16));
    }
  }
  unsigned us = *(const unsigned*)&hcol[node * 256];
  float rn = rnorm[node];
  float2 o;
  o.x = rn * (a0 + bf2f((unsigned short)us));
  o.y = rn * (a1 + bf2f((unsigned short)(us >> 16)));
  *(float2*)&out[(size_t)node * 256 + colbase + lane * 2] = o;
}

extern "C" void kernel_launch(void* const* d_in, const int* in_sizes, int n_in,
                              void* d_out, int out_size, void* d_ws, size_t ws_size,
                              hipStream_t stream) {
  const float* x = (const float*)d_in[0];
  const float* W = (const float*)d_in[1];
  const int* ei = (const int*)d_in[2];
  float* out = (float*)d_out;

  int N = in_sizes[0] / D;        // 100000
  int E = in_sizes[2] / 2;        // 3200000
  int NPAD = (N + 127) & ~127;
  const int* src = ei;
  const int* dst = ei + E;

  char* p = (char*)d_ws;
  auto alloc = [&](size_t b) {
    char* r = p;
    p += (b + 255) & ~(size_t)255;
    return r;
  };
  unsigned short* wb = (unsigned short*)alloc((size_t)D * D * 2);
  unsigned short* hb = (unsigned short*)alloc((size_t)NPAD * D * 2);
  int* csr = (int*)alloc((size_t)NBUCK << CAPSH << 2);   // strided: 25.6 MB
  int2* meta = (int2*)alloc((size_t)N * 8);
  float* rnorm = (float*)alloc((size_t)N * 4);
  int* gcursor = (int*)alloc(NBUCK * 4);
  // ebuf (NBUCK<<CAPSH ints = 25.6 MB) aliases hb (51 MB): dead before gemm
  int* ebuf = (int*)hb;

  init_kernel<<<2, 256, 0, stream>>>(gcursor);
  binscatter_kernel<<<(E + TILE - 1) / TILE, 256, 0, stream>>>(src, dst, gcursor, ebuf, E);
  bucketsort_kernel<<<NBUCK, 256, 0, stream>>>(ebuf, gcursor, csr, meta, rnorm, N);
  convw_kernel<<<(D * D / 4) / 256, 256, 0, stream>>>(W, wb);
  gemm_kernel<<<dim3(NPAD / 128, D / 128), 256, 0, stream>>>(x, wb, hb, rnorm, N);
  gather_kernel<<<2 * ((N + 3) / 4), 256, 0, stream>>>(hb, meta, rnorm, csr, out, N);
}